// Round 13
// baseline (271.821 us; speedup 1.0000x reference)
//
#include <hip/hip_runtime.h>

#define B_ 8
#define C_ 32
#define NI 256   // coarse positions (16x16)
#define C4 8192  // merged channels = 32*256

typedef _Float16 f16;
typedef __attribute__((ext_vector_type(8))) _Float16 f16x8;
typedef __attribute__((ext_vector_type(4))) _Float16 f16x4;
typedef __attribute__((ext_vector_type(2))) _Float16 f16x2;
typedef __attribute__((ext_vector_type(4))) float f32x4;

__device__ __forceinline__ int dh_of(int t) { return (t & 1) | ((t >> 1) & 2) | ((t >> 2) & 4) | ((t >> 3) & 8); }
__device__ __forceinline__ int dw_of(int t) { return ((t >> 1) & 1) | ((t >> 2) & 2) | ((t >> 3) & 4) | ((t >> 4) & 8); }
// t from pixel-in-tile (hl, w): bits t0=hl0,t1=w0,t2=hl1,t3=w1,t4=hl2,t5=w2,t6=hl3,t7=w3
__device__ __forceinline__ int t_of(int hl, int w) {
  return (hl & 1) | ((w & 1) << 1) | ((hl & 2) << 1) | ((w & 2) << 2)
       | ((hl & 4) << 2) | ((w & 4) << 3) | ((hl & 8) << 3) | ((w & 8) << 4);
}

// async 16B global -> LDS (gfx950). lds must be wave-uniform base; HW adds lane*16.
__device__ __forceinline__ void gld16(const void* g, void* lds) {
  __builtin_amdgcn_global_load_lds(
      (const __attribute__((address_space(1))) unsigned int*)g,
      (__attribute__((address_space(3))) unsigned int*)lds, 16, 0, 0);
}

// ---------------------------------------------------------------------------
// K1a (v5.1): LDS-staged depthwise 3x3 conv, block = (b, c, hi-strip).
// ROUND-13 CHANGE: __launch_bounds__(256,8) -- round-12's (256,4) capped
// residency at 4 blocks/CU while 19.97KB LDS fits 8; occupancy was 33%.
// VGPR=60 fits the 64-reg budget of 8 waves/EU.
// ---------------------------------------------------------------------------
template <bool WRITE_VTT>
__global__ __launch_bounds__(256, 8) void k1a_conv(
    const float* __restrict__ x, const float* __restrict__ wq, const float* __restrict__ bq,
    const float* __restrict__ wk, const float* __restrict__ bk,
    f16* __restrict__ Qn, f16* __restrict__ Kn, f16* __restrict__ Vtt)
{
  __shared__ __align__(16) float xs[19 * 260];   // 19.76 KB
  const int bid = blockIdx.x;
  const int hi = bid & 15, c = (bid >> 4) & 31, b = bid >> 9;
  const int tid = threadIdx.x;
  const size_t cimg = ((size_t)(b * 32 + c)) << 16;

  // zero the 4-col pad of every row (left-halo trick) -- 19 b128 writes
  if (tid < 19) {
    f32x4 z = {};
    *(f32x4*)&xs[tid * 260 + 256] = z;
  }
  // stage rows 1..18 (strip row rr = gh - (hi*16 - 1)), 1152 f32x4 units
#pragma unroll
  for (int s = 0; s < 5; ++s) {
    const int idx = tid + 256 * s;
    if (idx < 1152) {
      const int rr = idx >> 6;        // 0..17
      const int col4 = idx & 63;
      const int gh = hi * 16 - 1 + rr;
      f32x4 v = {};
      if ((unsigned)gh < 256u)
        v = *(const f32x4*)(x + cimg + (size_t)gh * 256 + col4 * 4);
      *(f32x4*)&xs[(rr + 1) * 260 + col4 * 4] = v;
    }
  }
  __syncthreads();

  // Q/K conv: thread = (hl = tid>>4, wseg = tid&15), 16 outputs along w
  {
    const int hl = tid >> 4, wseg = tid & 15;
    const int w0 = wseg * 16;
    float q[16], k[16];
    const float bqv = bq[c], bkv = bk[c];
#pragma unroll
    for (int w = 0; w < 16; ++w) { q[w] = bqv; k[w] = bkv; }
#pragma unroll
    for (int dy = 0; dy < 3; ++dy) {
      const float* row = &xs[(hl + 1 + dy) * 260];
      float rbuf[24];   // cols w0-4 .. w0+19 (aligned b128 x6)
#pragma unroll
      for (int v6 = 0; v6 < 6; ++v6) {
        const f32x4 a = *(const f32x4*)(row + w0 - 4 + 4 * v6);
#pragma unroll
        for (int e = 0; e < 4; ++e) rbuf[v6 * 4 + e] = a[e];
      }
      const float q0 = wq[c * 9 + dy * 3], q1 = wq[c * 9 + dy * 3 + 1], q2 = wq[c * 9 + dy * 3 + 2];
      const float k0 = wk[c * 9 + dy * 3], k1 = wk[c * 9 + dy * 3 + 1], k2 = wk[c * 9 + dy * 3 + 2];
#pragma unroll
      for (int w = 0; w < 16; ++w) {   // col w0+w-1 = rbuf[3+w]
        q[w] += rbuf[3 + w] * q0 + rbuf[4 + w] * q1 + rbuf[5 + w] * q2;
        k[w] += rbuf[3 + w] * k0 + rbuf[4 + w] * k1 + rbuf[5 + w] * k2;
      }
    }
    f16x8 qo[2], ko[2];
#pragma unroll
    for (int w = 0; w < 16; ++w) { qo[w >> 3][w & 7] = (f16)q[w]; ko[w >> 3][w & 7] = (f16)k[w]; }
    f16* qp = Qn + cimg + (size_t)(hi * 16 + hl) * 256 + w0;
    f16* kp = Kn + cimg + (size_t)(hi * 16 + hl) * 256 + w0;
    *(f16x8*)qp = qo[0]; *(f16x8*)(qp + 8) = qo[1];
    *(f16x8*)kp = ko[0]; *(f16x8*)(kp + 8) = ko[1];
  }

  if (WRITE_VTT) {  // Vtt[b][t*32+c][hi*16+wi] = xs[dh(t)+2][wi*16+dw(t)]
    const int t = tid;
    const int dh = dh_of(t), dw = dw_of(t);
    const float* src = &xs[(dh + 2) * 260 + dw];
    f16x8 o0, o1;
#pragma unroll
    for (int wi = 0; wi < 16; ++wi) {
      const f16 v = (f16)src[wi * 16];
      if (wi < 8) o0[wi] = v; else o1[wi - 8] = v;
    }
    f16* vdst = Vtt + ((size_t)b * C4 + (size_t)t * 32 + c) * 256 + hi * 16;
    *(f16x8*)vdst = o0;
    *(f16x8*)(vdst + 8) = o1;
  }
}

// ---------------------------------------------------------------------------
// K1v: V = x (f16), permuted to [b][i][c4] via one LDS transpose.
// (Vt consumed by K5's residual.)
// ---------------------------------------------------------------------------
__global__ __launch_bounds__(256) void k1v_permute(
    const float* __restrict__ x, f16* __restrict__ Vt)
{
  __shared__ f16 vls[32 * 273];   // odd stride spreads banks
  const int bid = blockIdx.x;
  const int b = bid >> 8, i = bid & 255;
  const int hi = i >> 4, wi = i & 15;
  const int tid = threadIdx.x;

#pragma unroll
  for (int tt = 0; tt < 2; ++tt) {
    const int c = (tid >> 4) + tt * 16, hl = tid & 15;
    const float* p = x + (((size_t)(b * 32 + c)) << 16) + (size_t)(hi * 16 + hl) * 256 + wi * 16;
    const f32x4 a0 = *(const f32x4*)(p);
    const f32x4 a1 = *(const f32x4*)(p + 4);
    const f32x4 a2 = *(const f32x4*)(p + 8);
    const f32x4 a3 = *(const f32x4*)(p + 12);
    float r[16];
#pragma unroll
    for (int e = 0; e < 4; ++e) { r[e] = a0[e]; r[4 + e] = a1[e]; r[8 + e] = a2[e]; r[12 + e] = a3[e]; }
#pragma unroll
    for (int w = 0; w < 16; ++w) vls[c * 273 + t_of(hl, w)] = (f16)r[w];
  }
  __syncthreads();

  f16x8 o[4];
#pragma unroll
  for (int c = 0; c < 32; ++c) o[c >> 3][c & 7] = vls[c * 273 + tid];
  f16x8* dst = (f16x8*)(Vt + ((size_t)(b * NI + i)) * C4 + (size_t)tid * 32);
  dst[0] = o[0]; dst[1] = o[1]; dst[2] = o[2]; dst[3] = o[3];
}

// ---------------------------------------------------------------------------
// K1t (fallback only, when ws too small to fuse Vtt into k1a):
// Vtt[b][c4][j] = V^T. block = (b, c, hi/2). Runs after K2 (Vtt aliases Kn).
// ---------------------------------------------------------------------------
__global__ __launch_bounds__(256) void k1t_vtt(
    const float* __restrict__ x, f16* __restrict__ Vtt)
{
  __shared__ __align__(16) f16 xls[16 * 264];
  const int hi2 = blockIdx.x, c = blockIdx.y, b = blockIdx.z;
  const int tid = threadIdx.x;
  const int dh = dh_of(tid), dw = dw_of(tid);
  const size_t cimg = ((size_t)(b * 32 + c)) << 16;
  f16* vrow = Vtt + ((size_t)b * C4 + (size_t)tid * 32 + c) * 256;

#pragma unroll
  for (int hp = 0; hp < 2; ++hp) {
    const int hi = hi2 * 2 + hp;
    {
      const int hl = tid >> 4, wseg = tid & 15;
      const float* p = x + cimg + (size_t)(hi * 16 + hl) * 256 + wseg * 16;
      const f32x4 a0 = *(const f32x4*)(p);
      const f32x4 a1 = *(const f32x4*)(p + 4);
      const f32x4 a2 = *(const f32x4*)(p + 8);
      const f32x4 a3 = *(const f32x4*)(p + 12);
      f16x8 h0, h1;
#pragma unroll
      for (int e = 0; e < 4; ++e) { h0[e] = (f16)a0[e]; h0[4 + e] = (f16)a1[e]; h1[e] = (f16)a2[e]; h1[4 + e] = (f16)a3[e]; }
      *(f16x8*)&xls[hl * 264 + wseg * 16] = h0;
      *(f16x8*)&xls[hl * 264 + wseg * 16 + 8] = h1;
    }
    __syncthreads();
    {
      f16x8 o0, o1;
#pragma unroll
      for (int wi = 0; wi < 16; ++wi) {
        const f16 v = xls[dh * 264 + wi * 16 + dw];
        if (wi < 8) o0[wi] = v; else o1[wi - 8] = v;
      }
      *(f16x8*)(vrow + hi * 16) = o0;
      *(f16x8*)(vrow + hi * 16 + 8) = o1;
    }
    __syncthreads();
  }
}

// ---------------------------------------------------------------------------
// K2: logits partials from NATURAL-layout Qn/Kn. Split-K by 4.
// ---------------------------------------------------------------------------
__global__ __launch_bounds__(256) void k2_logits(
    const f16* __restrict__ Qn, const f16* __restrict__ Kn, float* __restrict__ Spart)
{
  const int b = blockIdx.z;
  const int kt = blockIdx.y;
  const int it = blockIdx.x >> 2, jt = blockIdx.x & 3;
  const int tid = threadIdx.x, wave = tid >> 6, lane = tid & 63;
  const int li = lane & 15, lk = lane >> 4;
  const int i0 = it * 64 + wave * 16;
  const int j0 = jt * 64;
  const f16* Qb = Qn + ((size_t)b << 21);
  const f16* Kb = Kn + ((size_t)b << 21);
  const int dhl = lk >> 1, dwl = (lk & 1) * 8;

  f32x4 acc[4] = {};
  const int kbeg = kt * 2048, kend = kbeg + 2048;
  for (int kk = kbeg; kk < kend; kk += 32) {
    const int c = kk >> 8, dhb = (kk >> 4) & 15;
    const size_t cbase = ((size_t)c << 16) + (size_t)(dhb + dhl) * 256 + li * 16 + dwl;
    const f16x8 a = *(const f16x8*)(Qb + cbase + (size_t)i0 * 256);
#pragma unroll
    for (int jj = 0; jj < 4; ++jj) {
      const f16x8 bb = *(const f16x8*)(Kb + cbase + (size_t)(j0 + jj * 16) * 256);
      acc[jj] = __builtin_amdgcn_mfma_f32_16x16x32_f16(a, bb, acc[jj], 0, 0, 0);
    }
  }
  float* Sp = Spart + ((size_t)kt * B_ + b) * NI * NI;
#pragma unroll
  for (int jj = 0; jj < 4; ++jj)
#pragma unroll
    for (int r = 0; r < 4; ++r) {
      const int ii = i0 + lk * 4 + r;
      const int jc = j0 + jj * 16 + li;
      Sp[(size_t)ii * NI + jc] = acc[jj][r];
    }
}

// ---------------------------------------------------------------------------
// K3: sum 4 partials + softmax over j (256), write f16. One wave per row.
// ---------------------------------------------------------------------------
__global__ __launch_bounds__(256) void k3_softmax(
    const float* __restrict__ Spart, f16* __restrict__ Sh)
{
  const int row = blockIdx.x * 4 + (threadIdx.x >> 6);  // 2048 rows
  const int lane = threadIdx.x & 63;
  const size_t base = (size_t)row * NI + lane * 4;
  f32x4 v = {0.f, 0.f, 0.f, 0.f};
#pragma unroll
  for (int kt = 0; kt < 4; ++kt) {
    const f32x4 p = *(const f32x4*)(Spart + (size_t)kt * B_ * NI * NI + base);
    v[0] += p[0]; v[1] += p[1]; v[2] += p[2]; v[3] += p[3];
  }
  float m = fmaxf(fmaxf(v[0], v[1]), fmaxf(v[2], v[3]));
#pragma unroll
  for (int d = 1; d < 64; d <<= 1) m = fmaxf(m, __shfl_xor(m, d, 64));
  const float e0 = expf(v[0] - m), e1 = expf(v[1] - m), e2 = expf(v[2] - m), e3 = expf(v[3] - m);
  float s = e0 + e1 + e2 + e3;
#pragma unroll
  for (int d = 1; d < 64; d <<= 1) s += __shfl_xor(s, d, 64);
  const float inv = 1.f / s;
  f16x4 o;
  o[0] = (f16)(e0 * inv); o[1] = (f16)(e1 * inv); o[2] = (f16)(e2 * inv); o[3] = (f16)(e3 * inv);
  *(f16x4*)(Sh + (size_t)row * NI + lane * 4) = o;
}

// ---------------------------------------------------------------------------
// K4 (m97-structure): per-batch GEMM E[c4][i] = sum_j Vtt[c4][j]*Sh[i][j].
// Block tile 128x128, BK=64, LDS-staged A and B via global_load_lds width-16,
// 2-barrier K-loop, 4 waves (2x2), 512 MFMA/block.
// ---------------------------------------------------------------------------
__global__ __launch_bounds__(256) void k4_ev(
    const f16* __restrict__ Vtt, const f16* __restrict__ Sh, f16* __restrict__ Y)
{
  __shared__ __align__(16) f16 As[128 * 64];  // [m][k] linear, 16 KB
  __shared__ __align__(16) f16 Bs[128 * 64];  // [n][k] linear, 16 KB
  const int mt = blockIdx.x, nt = blockIdx.y, b = blockIdx.z;
  const int m0 = mt * 128, n0 = nt * 128;
  const int tid = threadIdx.x, wave = tid >> 6, lane = tid & 63;
  const int li = lane & 15, lk = lane >> 4;
  const int wm = wave >> 1, wn = wave & 1;
  const f16* Va  = Vtt + (size_t)b * C4 * NI;
  const f16* Shb = Sh + (size_t)b * NI * NI;

  const int srow = tid >> 3, scol = (tid & 7) * 8;

  f32x4 acc[4][4] = {};

#define K4_STAGE(k0)                                                          \
  {                                                                           \
    _Pragma("unroll")                                                         \
    for (int j = 0; j < 4; ++j) {                                             \
      const int rg = j * 32 + srow;                                           \
      gld16(Va + (size_t)(m0 + rg) * NI + (k0) + scol,                        \
            (char*)As + j * 4096 + wave * 1024);                              \
      gld16(Shb + (size_t)(n0 + rg) * NI + (k0) + scol,                       \
            (char*)Bs + j * 4096 + wave * 1024);                              \
    }                                                                         \
  }

  K4_STAGE(0);
#pragma unroll
  for (int kt = 0; kt < 4; ++kt) {
    __syncthreads();
#pragma unroll
    for (int kh = 0; kh < 2; ++kh) {
      f16x8 af[4], bf[4];
#pragma unroll
      for (int mi = 0; mi < 4; ++mi)
        af[mi] = *(const f16x8*)&As[(wm * 64 + mi * 16 + li) * 64 + kh * 32 + lk * 8];
#pragma unroll
      for (int ni = 0; ni < 4; ++ni)
        bf[ni] = *(const f16x8*)&Bs[(wn * 64 + ni * 16 + li) * 64 + kh * 32 + lk * 8];
#pragma unroll
      for (int mi = 0; mi < 4; ++mi)
#pragma unroll
        for (int ni = 0; ni < 4; ++ni)
          acc[mi][ni] = __builtin_amdgcn_mfma_f32_16x16x32_f16(af[mi], bf[ni], acc[mi][ni], 0, 0, 0);
    }
    __syncthreads();
    if (kt < 3) K4_STAGE((kt + 1) * 64);
  }
#undef K4_STAGE

#pragma unroll
  for (int mi = 0; mi < 4; ++mi)
#pragma unroll
    for (int ni = 0; ni < 4; ++ni) {
      const int i = n0 + wn * 64 + ni * 16 + li;
      const int m = m0 + wm * 64 + mi * 16 + lk * 4;
      f16x4 p;
#pragma unroll
      for (int r = 0; r < 4; ++r) p[r] = (f16)acc[mi][ni][r];
      *(f16x4*)(Y + ((size_t)(b * NI + i)) * C4 + m) = p;
    }
}

// ---------------------------------------------------------------------------
// K5: out[b,o,h,w] = sum_ci w1[o,ci] * (Y+V)[b, i(h,w), t(h,w)*32+ci], fp32.
// Residual fused here. block = (b, i): full 64B-line coverage on stores.
// ---------------------------------------------------------------------------
__global__ __launch_bounds__(256) void k5_w1_unpermute(
    const f16* __restrict__ Y, const f16* __restrict__ Vt,
    const float* __restrict__ w1, float* __restrict__ out)
{
  __shared__ f16 w1s[32 * 32];
  const int bid = blockIdx.x;
  const int b = bid >> 8, i = bid & 255;
  const int hi = i >> 4, wi = i & 15;
  const int tid = threadIdx.x;
#pragma unroll
  for (int e = 0; e < 4; ++e) w1s[tid + 256 * e] = (f16)w1[tid + 256 * e];
  __syncthreads();

  const int wave = tid >> 6, lane = tid & 63, li = lane & 15, lk = lane >> 4;
  const f16* Yrow = Y + ((size_t)(b * NI + i)) * C4;
  const f16* Vrow = Vt + ((size_t)(b * NI + i)) * C4;
  const f16x8 b0 = *(const f16x8*)(&w1s[li * 32 + lk * 8]);         // o = li
  const f16x8 b1 = *(const f16x8*)(&w1s[(16 + li) * 32 + lk * 8]);  // o = 16+li

#pragma unroll
  for (int q = 0; q < 4; ++q) {
    const int tt = wave * 4 + q;
    const size_t off = (size_t)(tt * 16 + li) * 32 + lk * 8;
    const f16x8 ya = *(const f16x8*)(Yrow + off);
    const f16x8 va = *(const f16x8*)(Vrow + off);
    f16x8 a;
#pragma unroll
    for (int e = 0; e < 8; ++e) a[e] = (f16)((float)ya[e] + (float)va[e]);
    f32x4 d0 = {}, d1 = {};
    d0 = __builtin_amdgcn_mfma_f32_16x16x32_f16(a, b0, d0, 0, 0, 0);
    d1 = __builtin_amdgcn_mfma_f32_16x16x32_f16(a, b1, d1, 0, 0, 0);
#pragma unroll
    for (int r = 0; r < 4; ++r) {
      const int t = tt * 16 + lk * 4 + r;
      const int dh = dh_of(t), dw = dw_of(t);
      const int h = hi * 16 + dh, w = wi * 16 + dw;
      out[(((size_t)(b * 32 + li)) * 256 + h) * 256 + w] = d0[r];
      out[(((size_t)(b * 32 + 16 + li)) * 256 + h) * 256 + w] = d1[r];
    }
  }
}

// ---------------------------------------------------------------------------
extern "C" void kernel_launch(void* const* d_in, const int* in_sizes, int n_in,
                              void* d_out, int out_size, void* d_ws, size_t ws_size,
                              hipStream_t stream)
{
  const float* x  = (const float*)d_in[0];
  const float* wq = (const float*)d_in[1];
  const float* bq = (const float*)d_in[2];
  const float* wk = (const float*)d_in[3];
  const float* bk = (const float*)d_in[4];
  const float* w1 = (const float*)d_in[5];
  float* out = (float*)d_out;
  char* ws = (char*)d_ws;

  const size_t M32 = 33554432;
  // fused layout needs Qn,Kn,Vt,Vtt (4x32M) + Spart 8M + Sh 1M = ~137 MiB
  const bool fused = ws_size >= 4 * M32 + 8388608 + 1048576;

  f16*   Qn = (f16*)(ws);
  f16*   Kn = (f16*)(ws + M32);
  f16*   Vt = (f16*)(ws + 2 * M32);
  f16*   Y  = Qn;  // Qn dead after K2

  if (fused) {
    f16*   Vtt   = (f16*)(ws + 3 * M32);
    float* Spart = (float*)(ws + 4 * M32);
    f16*   Sh    = (f16*)(ws + 4 * M32 + 8388608);
    k1a_conv<true><<<4096, 256, 0, stream>>>(x, wq, bq, wk, bk, Qn, Kn, Vtt);
    k1v_permute<<<2048, 256, 0, stream>>>(x, Vt);
    k2_logits<<<dim3(16, 4, 8), 256, 0, stream>>>(Qn, Kn, Spart);
    k3_softmax<<<512, 256, 0, stream>>>(Spart, Sh);
    k4_ev<<<dim3(64, 2, 8), 256, 0, stream>>>(Vtt, Sh, Y);
    k5_w1_unpermute<<<2048, 256, 0, stream>>>(Y, Vt, w1, out);
  } else {
    // fallback: Vtt aliases Kn (dead after K2), k1t runs after K3
    f16*   Vtt   = Kn;
    float* Spart = (float*)(ws + 100663296);
    f16*   Sh    = (f16*)(ws + 109051904);
    k1a_conv<false><<<4096, 256, 0, stream>>>(x, wq, bq, wk, bk, Qn, Kn, (f16*)nullptr);
    k1v_permute<<<2048, 256, 0, stream>>>(x, Vt);
    k2_logits<<<dim3(16, 4, 8), 256, 0, stream>>>(Qn, Kn, Spart);
    k3_softmax<<<512, 256, 0, stream>>>(Spart, Sh);
    k1t_vtt<<<dim3(8, 32, 8), 256, 0, stream>>>(x, Vtt);
    k4_ev<<<dim3(64, 2, 8), 256, 0, stream>>>(Vtt, Sh, Y);
    k5_w1_unpermute<<<2048, 256, 0, stream>>>(Y, Vt, w1, out);
  }
}

// Round 14
// 202.807 us; speedup vs baseline: 1.3403x; 1.3403x over previous
//
#include <hip/hip_runtime.h>

#define B_ 8
#define C_ 32
#define NI 256   // coarse positions (16x16)
#define C4 8192  // merged channels = 32*256

typedef _Float16 f16;
typedef __attribute__((ext_vector_type(8))) _Float16 f16x8;
typedef __attribute__((ext_vector_type(4))) _Float16 f16x4;
typedef __attribute__((ext_vector_type(2))) _Float16 f16x2;
typedef __attribute__((ext_vector_type(4))) float f32x4;

__device__ __forceinline__ int dh_of(int t) { return (t & 1) | ((t >> 1) & 2) | ((t >> 2) & 4) | ((t >> 3) & 8); }
__device__ __forceinline__ int dw_of(int t) { return ((t >> 1) & 1) | ((t >> 2) & 2) | ((t >> 3) & 4) | ((t >> 4) & 8); }

// async 16B global -> LDS (gfx950). lds must be wave-uniform base; HW adds lane*16.
__device__ __forceinline__ void gld16(const void* g, void* lds) {
  __builtin_amdgcn_global_load_lds(
      (const __attribute__((address_space(1))) unsigned int*)g,
      (__attribute__((address_space(3))) unsigned int*)lds, 16, 0, 0);
}

// ---------------------------------------------------------------------------
// K1a (v5.2): LDS-staged depthwise 3x3 conv + fused Vtt emission.
// __launch_bounds__(256,6): VGPR cap 85 fits the ~60-reg live set (round-13:
// cap 64 at (256,8) -> allocator gave up, VGPR=32 + 240MB scratch spills;
// round-12: (256,4) left residency at 4 blocks/CU, occupancy 33%).
// ---------------------------------------------------------------------------
__global__ __launch_bounds__(256, 6) void k1a_conv(
    const float* __restrict__ x, const float* __restrict__ wq, const float* __restrict__ bq,
    const float* __restrict__ wk, const float* __restrict__ bk,
    f16* __restrict__ Qn, f16* __restrict__ Kn, f16* __restrict__ Vtt)
{
  __shared__ __align__(16) float xs[19 * 260];   // 19.76 KB
  const int bid = blockIdx.x;
  const int hi = bid & 15, c = (bid >> 4) & 31, b = bid >> 9;
  const int tid = threadIdx.x;
  const size_t cimg = ((size_t)(b * 32 + c)) << 16;

  // zero the 4-col pad of every row (left-halo trick) -- 19 b128 writes
  if (tid < 19) {
    f32x4 z = {};
    *(f32x4*)&xs[tid * 260 + 256] = z;
  }
  // stage rows 1..18 (strip row rr = gh - (hi*16 - 1)), 1152 f32x4 units
#pragma unroll
  for (int s = 0; s < 5; ++s) {
    const int idx = tid + 256 * s;
    if (idx < 1152) {
      const int rr = idx >> 6;        // 0..17
      const int col4 = idx & 63;
      const int gh = hi * 16 - 1 + rr;
      f32x4 v = {};
      if ((unsigned)gh < 256u)
        v = *(const f32x4*)(x + cimg + (size_t)gh * 256 + col4 * 4);
      *(f32x4*)&xs[(rr + 1) * 260 + col4 * 4] = v;
    }
  }
  __syncthreads();

  // Q/K conv: thread = (hl = tid>>4, wseg = tid&15), 16 outputs along w
  {
    const int hl = tid >> 4, wseg = tid & 15;
    const int w0 = wseg * 16;
    float q[16], k[16];
    const float bqv = bq[c], bkv = bk[c];
#pragma unroll
    for (int w = 0; w < 16; ++w) { q[w] = bqv; k[w] = bkv; }
#pragma unroll
    for (int dy = 0; dy < 3; ++dy) {
      const float* row = &xs[(hl + 1 + dy) * 260];
      float rbuf[24];   // cols w0-4 .. w0+19 (aligned b128 x6)
#pragma unroll
      for (int v6 = 0; v6 < 6; ++v6) {
        const f32x4 a = *(const f32x4*)(row + w0 - 4 + 4 * v6);
#pragma unroll
        for (int e = 0; e < 4; ++e) rbuf[v6 * 4 + e] = a[e];
      }
      const float q0 = wq[c * 9 + dy * 3], q1 = wq[c * 9 + dy * 3 + 1], q2 = wq[c * 9 + dy * 3 + 2];
      const float k0 = wk[c * 9 + dy * 3], k1 = wk[c * 9 + dy * 3 + 1], k2 = wk[c * 9 + dy * 3 + 2];
#pragma unroll
      for (int w = 0; w < 16; ++w) {   // col w0+w-1 = rbuf[3+w]
        q[w] += rbuf[3 + w] * q0 + rbuf[4 + w] * q1 + rbuf[5 + w] * q2;
        k[w] += rbuf[3 + w] * k0 + rbuf[4 + w] * k1 + rbuf[5 + w] * k2;
      }
    }
    f16x8 qo[2], ko[2];
#pragma unroll
    for (int w = 0; w < 16; ++w) { qo[w >> 3][w & 7] = (f16)q[w]; ko[w >> 3][w & 7] = (f16)k[w]; }
    f16* qp = Qn + cimg + (size_t)(hi * 16 + hl) * 256 + w0;
    f16* kp = Kn + cimg + (size_t)(hi * 16 + hl) * 256 + w0;
    *(f16x8*)qp = qo[0]; *(f16x8*)(qp + 8) = qo[1];
    *(f16x8*)kp = ko[0]; *(f16x8*)(kp + 8) = ko[1];
  }

  {  // Vtt[b][t*32+c][hi*16+wi] = xs[dh(t)+2][wi*16+dw(t)]
    const int t = tid;
    const int dh = dh_of(t), dw = dw_of(t);
    const float* src = &xs[(dh + 2) * 260 + dw];
    f16x8 o0, o1;
#pragma unroll
    for (int wi = 0; wi < 16; ++wi) {
      const f16 v = (f16)src[wi * 16];
      if (wi < 8) o0[wi] = v; else o1[wi - 8] = v;
    }
    f16* vdst = Vtt + ((size_t)b * C4 + (size_t)t * 32 + c) * 256 + hi * 16;
    *(f16x8*)vdst = o0;
    *(f16x8*)(vdst + 8) = o1;
  }
}

// ---------------------------------------------------------------------------
// K2: logits partials from NATURAL-layout Qn/Kn. Split-K by 4.
// ---------------------------------------------------------------------------
__global__ __launch_bounds__(256) void k2_logits(
    const f16* __restrict__ Qn, const f16* __restrict__ Kn, float* __restrict__ Spart)
{
  const int b = blockIdx.z;
  const int kt = blockIdx.y;
  const int it = blockIdx.x >> 2, jt = blockIdx.x & 3;
  const int tid = threadIdx.x, wave = tid >> 6, lane = tid & 63;
  const int li = lane & 15, lk = lane >> 4;
  const int i0 = it * 64 + wave * 16;
  const int j0 = jt * 64;
  const f16* Qb = Qn + ((size_t)b << 21);
  const f16* Kb = Kn + ((size_t)b << 21);
  const int dhl = lk >> 1, dwl = (lk & 1) * 8;

  f32x4 acc[4] = {};
  const int kbeg = kt * 2048, kend = kbeg + 2048;
  for (int kk = kbeg; kk < kend; kk += 32) {
    const int c = kk >> 8, dhb = (kk >> 4) & 15;
    const size_t cbase = ((size_t)c << 16) + (size_t)(dhb + dhl) * 256 + li * 16 + dwl;
    const f16x8 a = *(const f16x8*)(Qb + cbase + (size_t)i0 * 256);
#pragma unroll
    for (int jj = 0; jj < 4; ++jj) {
      const f16x8 bb = *(const f16x8*)(Kb + cbase + (size_t)(j0 + jj * 16) * 256);
      acc[jj] = __builtin_amdgcn_mfma_f32_16x16x32_f16(a, bb, acc[jj], 0, 0, 0);
    }
  }
  float* Sp = Spart + ((size_t)kt * B_ + b) * NI * NI;
#pragma unroll
  for (int jj = 0; jj < 4; ++jj)
#pragma unroll
    for (int r = 0; r < 4; ++r) {
      const int ii = i0 + lk * 4 + r;
      const int jc = j0 + jj * 16 + li;
      Sp[(size_t)ii * NI + jc] = acc[jj][r];
    }
}

// ---------------------------------------------------------------------------
// K3: sum 4 partials + softmax over j (256), write f16. One wave per row.
// ---------------------------------------------------------------------------
__global__ __launch_bounds__(256) void k3_softmax(
    const float* __restrict__ Spart, f16* __restrict__ Sh)
{
  const int row = blockIdx.x * 4 + (threadIdx.x >> 6);  // 2048 rows
  const int lane = threadIdx.x & 63;
  const size_t base = (size_t)row * NI + lane * 4;
  f32x4 v = {0.f, 0.f, 0.f, 0.f};
#pragma unroll
  for (int kt = 0; kt < 4; ++kt) {
    const f32x4 p = *(const f32x4*)(Spart + (size_t)kt * B_ * NI * NI + base);
    v[0] += p[0]; v[1] += p[1]; v[2] += p[2]; v[3] += p[3];
  }
  float m = fmaxf(fmaxf(v[0], v[1]), fmaxf(v[2], v[3]));
#pragma unroll
  for (int d = 1; d < 64; d <<= 1) m = fmaxf(m, __shfl_xor(m, d, 64));
  const float e0 = expf(v[0] - m), e1 = expf(v[1] - m), e2 = expf(v[2] - m), e3 = expf(v[3] - m);
  float s = e0 + e1 + e2 + e3;
#pragma unroll
  for (int d = 1; d < 64; d <<= 1) s += __shfl_xor(s, d, 64);
  const float inv = 1.f / s;
  f16x4 o;
  o[0] = (f16)(e0 * inv); o[1] = (f16)(e1 * inv); o[2] = (f16)(e2 * inv); o[3] = (f16)(e3 * inv);
  *(f16x4*)(Sh + (size_t)row * NI + lane * 4) = o;
}

// ---------------------------------------------------------------------------
// K4 (m97-structure + fused residual): per-batch GEMM
// Y[i][c4] = sum_j Vtt[c4][j]*Sh[i][j] + Vtt[c4][i].
// Block tile 128x128, BK=64, global_load_lds staging, 2-barrier K-loop.
// Residual read is coalesced (lanes li -> consecutive i within Vtt row m).
// ---------------------------------------------------------------------------
__global__ __launch_bounds__(256) void k4_ev(
    const f16* __restrict__ Vtt, const f16* __restrict__ Sh, f16* __restrict__ Y)
{
  __shared__ __align__(16) f16 As[128 * 64];  // [m][k] linear, 16 KB
  __shared__ __align__(16) f16 Bs[128 * 64];  // [n][k] linear, 16 KB
  const int mt = blockIdx.x, nt = blockIdx.y, b = blockIdx.z;
  const int m0 = mt * 128, n0 = nt * 128;
  const int tid = threadIdx.x, wave = tid >> 6, lane = tid & 63;
  const int li = lane & 15, lk = lane >> 4;
  const int wm = wave >> 1, wn = wave & 1;
  const f16* Va  = Vtt + (size_t)b * C4 * NI;
  const f16* Shb = Sh + (size_t)b * NI * NI;

  const int srow = tid >> 3, scol = (tid & 7) * 8;

  f32x4 acc[4][4] = {};

#define K4_STAGE(k0)                                                          \
  {                                                                           \
    _Pragma("unroll")                                                         \
    for (int j = 0; j < 4; ++j) {                                             \
      const int rg = j * 32 + srow;                                           \
      gld16(Va + (size_t)(m0 + rg) * NI + (k0) + scol,                        \
            (char*)As + j * 4096 + wave * 1024);                              \
      gld16(Shb + (size_t)(n0 + rg) * NI + (k0) + scol,                       \
            (char*)Bs + j * 4096 + wave * 1024);                              \
    }                                                                         \
  }

  K4_STAGE(0);
#pragma unroll
  for (int kt = 0; kt < 4; ++kt) {
    __syncthreads();
#pragma unroll
    for (int kh = 0; kh < 2; ++kh) {
      f16x8 af[4], bf[4];
#pragma unroll
      for (int mi = 0; mi < 4; ++mi)
        af[mi] = *(const f16x8*)&As[(wm * 64 + mi * 16 + li) * 64 + kh * 32 + lk * 8];
#pragma unroll
      for (int ni = 0; ni < 4; ++ni)
        bf[ni] = *(const f16x8*)&Bs[(wn * 64 + ni * 16 + li) * 64 + kh * 32 + lk * 8];
#pragma unroll
      for (int mi = 0; mi < 4; ++mi)
#pragma unroll
        for (int ni = 0; ni < 4; ++ni)
          acc[mi][ni] = __builtin_amdgcn_mfma_f32_16x16x32_f16(af[mi], bf[ni], acc[mi][ni], 0, 0, 0);
    }
    __syncthreads();
    if (kt < 3) K4_STAGE((kt + 1) * 64);
  }
#undef K4_STAGE

#pragma unroll
  for (int mi = 0; mi < 4; ++mi)
#pragma unroll
    for (int ni = 0; ni < 4; ++ni) {
      const int i = n0 + wn * 64 + ni * 16 + li;
      const int m = m0 + wm * 64 + mi * 16 + lk * 4;
      const f16* vres = Va + (size_t)m * NI + i;   // Vtt[b][m+r][i]
      f16x4 p;
#pragma unroll
      for (int r = 0; r < 4; ++r)
        p[r] = (f16)(acc[mi][ni][r] + (float)vres[(size_t)r * NI]);
      *(f16x4*)(Y + ((size_t)(b * NI + i)) * C4 + m) = p;
    }
}

// ---------------------------------------------------------------------------
// K5: out[b,o,h,w] = sum_ci w1[o,ci] * Y[b, i(h,w), t(h,w)*32+ci], fp32.
// (Residual now folded into Y by K4.) block = (b, i): full 64B-line coverage.
// ---------------------------------------------------------------------------
__global__ __launch_bounds__(256) void k5_w1_unpermute(
    const f16* __restrict__ Y, const float* __restrict__ w1, float* __restrict__ out)
{
  __shared__ f16 w1s[32 * 32];
  const int bid = blockIdx.x;
  const int b = bid >> 8, i = bid & 255;
  const int hi = i >> 4, wi = i & 15;
  const int tid = threadIdx.x;
#pragma unroll
  for (int e = 0; e < 4; ++e) w1s[tid + 256 * e] = (f16)w1[tid + 256 * e];
  __syncthreads();

  const int wave = tid >> 6, lane = tid & 63, li = lane & 15, lk = lane >> 4;
  const f16* Yrow = Y + ((size_t)(b * NI + i)) * C4;
  const f16x8 b0 = *(const f16x8*)(&w1s[li * 32 + lk * 8]);         // o = li
  const f16x8 b1 = *(const f16x8*)(&w1s[(16 + li) * 32 + lk * 8]);  // o = 16+li

#pragma unroll
  for (int q = 0; q < 4; ++q) {
    const int tt = wave * 4 + q;
    const f16x8 a = *(const f16x8*)(Yrow + (size_t)(tt * 16 + li) * 32 + lk * 8);
    f32x4 d0 = {}, d1 = {};
    d0 = __builtin_amdgcn_mfma_f32_16x16x32_f16(a, b0, d0, 0, 0, 0);
    d1 = __builtin_amdgcn_mfma_f32_16x16x32_f16(a, b1, d1, 0, 0, 0);
#pragma unroll
    for (int r = 0; r < 4; ++r) {
      const int t = tt * 16 + lk * 4 + r;
      const int dh = dh_of(t), dw = dw_of(t);
      const int h = hi * 16 + dh, w = wi * 16 + dw;
      out[(((size_t)(b * 32 + li)) * 256 + h) * 256 + w] = d0[r];
      out[(((size_t)(b * 32 + 16 + li)) * 256 + h) * 256 + w] = d1[r];
    }
  }
}

// ---------------------------------------------------------------------------
extern "C" void kernel_launch(void* const* d_in, const int* in_sizes, int n_in,
                              void* d_out, int out_size, void* d_ws, size_t ws_size,
                              hipStream_t stream)
{
  const float* x  = (const float*)d_in[0];
  const float* wq = (const float*)d_in[1];
  const float* bq = (const float*)d_in[2];
  const float* wk = (const float*)d_in[3];
  const float* bk = (const float*)d_in[4];
  const float* w1 = (const float*)d_in[5];
  float* out = (float*)d_out;
  char* ws = (char*)d_ws;

  // ws: Qn [0,32M) | Kn [32M,64M) | Vtt [64M,96M) | Spart [96M,104M) | Sh [104M,105M)
  // Y aliases Qn (dead after K2). Vt/k1v eliminated (residual fused in K4).
  f16*   Qn    = (f16*)(ws);
  f16*   Kn    = (f16*)(ws + 33554432);
  f16*   Vtt   = (f16*)(ws + 67108864);
  float* Spart = (float*)(ws + 100663296);
  f16*   Sh    = (f16*)(ws + 109051904);
  f16*   Y     = Qn;

  k1a_conv<<<4096, 256, 0, stream>>>(x, wq, bq, wk, bk, Qn, Kn, Vtt);
  k2_logits<<<dim3(16, 4, 8), 256, 0, stream>>>(Qn, Kn, Spart);
  k3_softmax<<<512, 256, 0, stream>>>(Spart, Sh);
  k4_ev<<<dim3(64, 2, 8), 256, 0, stream>>>(Vtt, Sh, Y);
  k5_w1_unpermute<<<2048, 256, 0, stream>>>(Y, w1, out);
}

// Round 15
// 136.794 us; speedup vs baseline: 1.9871x; 1.4826x over previous
//
#include <hip/hip_runtime.h>

#define B_ 8
#define C_ 32
#define NI 256   // coarse positions (16x16)
#define C4 8192  // merged channels = 32*256

typedef _Float16 f16;
typedef __attribute__((ext_vector_type(8))) _Float16 f16x8;
typedef __attribute__((ext_vector_type(4))) _Float16 f16x4;
typedef __attribute__((ext_vector_type(2))) _Float16 f16x2;
typedef __attribute__((ext_vector_type(4))) float f32x4;

__device__ __forceinline__ int dh_of(int t) { return (t & 1) | ((t >> 1) & 2) | ((t >> 2) & 4) | ((t >> 3) & 8); }
__device__ __forceinline__ int dw_of(int t) { return ((t >> 1) & 1) | ((t >> 2) & 2) | ((t >> 3) & 4) | ((t >> 4) & 8); }

// async 16B global -> LDS (gfx950). lds must be wave-uniform base; HW adds lane*16.
__device__ __forceinline__ void gld16(const void* g, void* lds) {
  __builtin_amdgcn_global_load_lds(
      (const __attribute__((address_space(1))) unsigned int*)g,
      (__attribute__((address_space(3))) unsigned int*)lds, 16, 0, 0);
}

// ---------------------------------------------------------------------------
// K1a (v5.3): LDS-staged depthwise 3x3 conv + fused Vtt emission.
// PLAIN __launch_bounds__(256): no min-waves arg. Toolchain map (this kernel):
//   (256,4): VGPR=60, no spill, 54us, occ 33% (residency capped at 4)
//   (256,6)/(256,8): allocator pathology -- VGPR 40/32 + >150MB scratch
// Plain: allocator free (observed default = reg-minimizing, spill-free);
// residency then LDS-limited at 8 blocks/CU (19.97KB).
// ---------------------------------------------------------------------------
__global__ __launch_bounds__(256) void k1a_conv(
    const float* __restrict__ x, const float* __restrict__ wq, const float* __restrict__ bq,
    const float* __restrict__ wk, const float* __restrict__ bk,
    f16* __restrict__ Qn, f16* __restrict__ Kn, f16* __restrict__ Vtt)
{
  __shared__ __align__(16) float xs[19 * 260];   // 19.76 KB
  const int bid = blockIdx.x;
  const int hi = bid & 15, c = (bid >> 4) & 31, b = bid >> 9;
  const int tid = threadIdx.x;
  const size_t cimg = ((size_t)(b * 32 + c)) << 16;

  // zero the 4-col pad of every row (left-halo trick) -- 19 b128 writes
  if (tid < 19) {
    f32x4 z = {};
    *(f32x4*)&xs[tid * 260 + 256] = z;
  }
  // stage rows 1..18 (strip row rr = gh - (hi*16 - 1)), 1152 f32x4 units
#pragma unroll
  for (int s = 0; s < 5; ++s) {
    const int idx = tid + 256 * s;
    if (idx < 1152) {
      const int rr = idx >> 6;        // 0..17
      const int col4 = idx & 63;
      const int gh = hi * 16 - 1 + rr;
      f32x4 v = {};
      if ((unsigned)gh < 256u)
        v = *(const f32x4*)(x + cimg + (size_t)gh * 256 + col4 * 4);
      *(f32x4*)&xs[(rr + 1) * 260 + col4 * 4] = v;
    }
  }
  __syncthreads();

  // Q/K conv: thread = (hl = tid>>4, wseg = tid&15), 16 outputs along w
  {
    const int hl = tid >> 4, wseg = tid & 15;
    const int w0 = wseg * 16;
    float q[16], k[16];
    const float bqv = bq[c], bkv = bk[c];
#pragma unroll
    for (int w = 0; w < 16; ++w) { q[w] = bqv; k[w] = bkv; }
#pragma unroll
    for (int dy = 0; dy < 3; ++dy) {
      const float* row = &xs[(hl + 1 + dy) * 260];
      float rbuf[24];   // cols w0-4 .. w0+19 (aligned b128 x6)
#pragma unroll
      for (int v6 = 0; v6 < 6; ++v6) {
        const f32x4 a = *(const f32x4*)(row + w0 - 4 + 4 * v6);
#pragma unroll
        for (int e = 0; e < 4; ++e) rbuf[v6 * 4 + e] = a[e];
      }
      const float q0 = wq[c * 9 + dy * 3], q1 = wq[c * 9 + dy * 3 + 1], q2 = wq[c * 9 + dy * 3 + 2];
      const float k0 = wk[c * 9 + dy * 3], k1 = wk[c * 9 + dy * 3 + 1], k2 = wk[c * 9 + dy * 3 + 2];
#pragma unroll
      for (int w = 0; w < 16; ++w) {   // col w0+w-1 = rbuf[3+w]
        q[w] += rbuf[3 + w] * q0 + rbuf[4 + w] * q1 + rbuf[5 + w] * q2;
        k[w] += rbuf[3 + w] * k0 + rbuf[4 + w] * k1 + rbuf[5 + w] * k2;
      }
    }
    f16x8 qo[2], ko[2];
#pragma unroll
    for (int w = 0; w < 16; ++w) { qo[w >> 3][w & 7] = (f16)q[w]; ko[w >> 3][w & 7] = (f16)k[w]; }
    f16* qp = Qn + cimg + (size_t)(hi * 16 + hl) * 256 + w0;
    f16* kp = Kn + cimg + (size_t)(hi * 16 + hl) * 256 + w0;
    *(f16x8*)qp = qo[0]; *(f16x8*)(qp + 8) = qo[1];
    *(f16x8*)kp = ko[0]; *(f16x8*)(kp + 8) = ko[1];
  }

  {  // Vtt[b][t*32+c][hi*16+wi] = xs[dh(t)+2][wi*16+dw(t)]
    const int t = tid;
    const int dh = dh_of(t), dw = dw_of(t);
    const float* src = &xs[(dh + 2) * 260 + dw];
    f16x8 o0, o1;
#pragma unroll
    for (int wi = 0; wi < 16; ++wi) {
      const f16 v = (f16)src[wi * 16];
      if (wi < 8) o0[wi] = v; else o1[wi - 8] = v;
    }
    f16* vdst = Vtt + ((size_t)b * C4 + (size_t)t * 32 + c) * 256 + hi * 16;
    *(f16x8*)vdst = o0;
    *(f16x8*)(vdst + 8) = o1;
  }
}

// ---------------------------------------------------------------------------
// K2: logits partials from NATURAL-layout Qn/Kn. Split-K by 4.
// ---------------------------------------------------------------------------
__global__ __launch_bounds__(256) void k2_logits(
    const f16* __restrict__ Qn, const f16* __restrict__ Kn, float* __restrict__ Spart)
{
  const int b = blockIdx.z;
  const int kt = blockIdx.y;
  const int it = blockIdx.x >> 2, jt = blockIdx.x & 3;
  const int tid = threadIdx.x, wave = tid >> 6, lane = tid & 63;
  const int li = lane & 15, lk = lane >> 4;
  const int i0 = it * 64 + wave * 16;
  const int j0 = jt * 64;
  const f16* Qb = Qn + ((size_t)b << 21);
  const f16* Kb = Kn + ((size_t)b << 21);
  const int dhl = lk >> 1, dwl = (lk & 1) * 8;

  f32x4 acc[4] = {};
  const int kbeg = kt * 2048, kend = kbeg + 2048;
  for (int kk = kbeg; kk < kend; kk += 32) {
    const int c = kk >> 8, dhb = (kk >> 4) & 15;
    const size_t cbase = ((size_t)c << 16) + (size_t)(dhb + dhl) * 256 + li * 16 + dwl;
    const f16x8 a = *(const f16x8*)(Qb + cbase + (size_t)i0 * 256);
#pragma unroll
    for (int jj = 0; jj < 4; ++jj) {
      const f16x8 bb = *(const f16x8*)(Kb + cbase + (size_t)(j0 + jj * 16) * 256);
      acc[jj] = __builtin_amdgcn_mfma_f32_16x16x32_f16(a, bb, acc[jj], 0, 0, 0);
    }
  }
  float* Sp = Spart + ((size_t)kt * B_ + b) * NI * NI;
#pragma unroll
  for (int jj = 0; jj < 4; ++jj)
#pragma unroll
    for (int r = 0; r < 4; ++r) {
      const int ii = i0 + lk * 4 + r;
      const int jc = j0 + jj * 16 + li;
      Sp[(size_t)ii * NI + jc] = acc[jj][r];
    }
}

// ---------------------------------------------------------------------------
// K3: sum 4 partials + softmax over j (256), write f16. One wave per row.
// ---------------------------------------------------------------------------
__global__ __launch_bounds__(256) void k3_softmax(
    const float* __restrict__ Spart, f16* __restrict__ Sh)
{
  const int row = blockIdx.x * 4 + (threadIdx.x >> 6);  // 2048 rows
  const int lane = threadIdx.x & 63;
  const size_t base = (size_t)row * NI + lane * 4;
  f32x4 v = {0.f, 0.f, 0.f, 0.f};
#pragma unroll
  for (int kt = 0; kt < 4; ++kt) {
    const f32x4 p = *(const f32x4*)(Spart + (size_t)kt * B_ * NI * NI + base);
    v[0] += p[0]; v[1] += p[1]; v[2] += p[2]; v[3] += p[3];
  }
  float m = fmaxf(fmaxf(v[0], v[1]), fmaxf(v[2], v[3]));
#pragma unroll
  for (int d = 1; d < 64; d <<= 1) m = fmaxf(m, __shfl_xor(m, d, 64));
  const float e0 = expf(v[0] - m), e1 = expf(v[1] - m), e2 = expf(v[2] - m), e3 = expf(v[3] - m);
  float s = e0 + e1 + e2 + e3;
#pragma unroll
  for (int d = 1; d < 64; d <<= 1) s += __shfl_xor(s, d, 64);
  const float inv = 1.f / s;
  f16x4 o;
  o[0] = (f16)(e0 * inv); o[1] = (f16)(e1 * inv); o[2] = (f16)(e2 * inv); o[3] = (f16)(e3 * inv);
  *(f16x4*)(Sh + (size_t)row * NI + lane * 4) = o;
}

// ---------------------------------------------------------------------------
// K4 (m97-structure + fused residual): per-batch GEMM
// Y[i][c4] = sum_j Vtt[c4][j]*Sh[i][j] + Vtt[c4][i].
// Block tile 128x128, BK=64, global_load_lds staging, 2-barrier K-loop.
// ---------------------------------------------------------------------------
__global__ __launch_bounds__(256) void k4_ev(
    const f16* __restrict__ Vtt, const f16* __restrict__ Sh, f16* __restrict__ Y)
{
  __shared__ __align__(16) f16 As[128 * 64];  // [m][k] linear, 16 KB
  __shared__ __align__(16) f16 Bs[128 * 64];  // [n][k] linear, 16 KB
  const int mt = blockIdx.x, nt = blockIdx.y, b = blockIdx.z;
  const int m0 = mt * 128, n0 = nt * 128;
  const int tid = threadIdx.x, wave = tid >> 6, lane = tid & 63;
  const int li = lane & 15, lk = lane >> 4;
  const int wm = wave >> 1, wn = wave & 1;
  const f16* Va  = Vtt + (size_t)b * C4 * NI;
  const f16* Shb = Sh + (size_t)b * NI * NI;

  const int srow = tid >> 3, scol = (tid & 7) * 8;

  f32x4 acc[4][4] = {};

#define K4_STAGE(k0)                                                          \
  {                                                                           \
    _Pragma("unroll")                                                         \
    for (int j = 0; j < 4; ++j) {                                             \
      const int rg = j * 32 + srow;                                           \
      gld16(Va + (size_t)(m0 + rg) * NI + (k0) + scol,                        \
            (char*)As + j * 4096 + wave * 1024);                              \
      gld16(Shb + (size_t)(n0 + rg) * NI + (k0) + scol,                       \
            (char*)Bs + j * 4096 + wave * 1024);                              \
    }                                                                         \
  }

  K4_STAGE(0);
#pragma unroll
  for (int kt = 0; kt < 4; ++kt) {
    __syncthreads();
#pragma unroll
    for (int kh = 0; kh < 2; ++kh) {
      f16x8 af[4], bf[4];
#pragma unroll
      for (int mi = 0; mi < 4; ++mi)
        af[mi] = *(const f16x8*)&As[(wm * 64 + mi * 16 + li) * 64 + kh * 32 + lk * 8];
#pragma unroll
      for (int ni = 0; ni < 4; ++ni)
        bf[ni] = *(const f16x8*)&Bs[(wn * 64 + ni * 16 + li) * 64 + kh * 32 + lk * 8];
#pragma unroll
      for (int mi = 0; mi < 4; ++mi)
#pragma unroll
        for (int ni = 0; ni < 4; ++ni)
          acc[mi][ni] = __builtin_amdgcn_mfma_f32_16x16x32_f16(af[mi], bf[ni], acc[mi][ni], 0, 0, 0);
    }
    __syncthreads();
    if (kt < 3) K4_STAGE((kt + 1) * 64);
  }
#undef K4_STAGE

#pragma unroll
  for (int mi = 0; mi < 4; ++mi)
#pragma unroll
    for (int ni = 0; ni < 4; ++ni) {
      const int i = n0 + wn * 64 + ni * 16 + li;
      const int m = m0 + wm * 64 + mi * 16 + lk * 4;
      const f16* vres = Va + (size_t)m * NI + i;   // Vtt[b][m+r][i]
      f16x4 p;
#pragma unroll
      for (int r = 0; r < 4; ++r)
        p[r] = (f16)(acc[mi][ni][r] + (float)vres[(size_t)r * NI]);
      *(f16x4*)(Y + ((size_t)(b * NI + i)) * C4 + m) = p;
    }
}

// ---------------------------------------------------------------------------
// K5: out[b,o,h,w] = sum_ci w1[o,ci] * Y[b, i(h,w), t(h,w)*32+ci], fp32.
// (Residual folded into Y by K4.) block = (b, i): full 64B-line coverage.
// ---------------------------------------------------------------------------
__global__ __launch_bounds__(256) void k5_w1_unpermute(
    const f16* __restrict__ Y, const float* __restrict__ w1, float* __restrict__ out)
{
  __shared__ f16 w1s[32 * 32];
  const int bid = blockIdx.x;
  const int b = bid >> 8, i = bid & 255;
  const int hi = i >> 4, wi = i & 15;
  const int tid = threadIdx.x;
#pragma unroll
  for (int e = 0; e < 4; ++e) w1s[tid + 256 * e] = (f16)w1[tid + 256 * e];
  __syncthreads();

  const int wave = tid >> 6, lane = tid & 63, li = lane & 15, lk = lane >> 4;
  const f16* Yrow = Y + ((size_t)(b * NI + i)) * C4;
  const f16x8 b0 = *(const f16x8*)(&w1s[li * 32 + lk * 8]);         // o = li
  const f16x8 b1 = *(const f16x8*)(&w1s[(16 + li) * 32 + lk * 8]);  // o = 16+li

#pragma unroll
  for (int q = 0; q < 4; ++q) {
    const int tt = wave * 4 + q;
    const f16x8 a = *(const f16x8*)(Yrow + (size_t)(tt * 16 + li) * 32 + lk * 8);
    f32x4 d0 = {}, d1 = {};
    d0 = __builtin_amdgcn_mfma_f32_16x16x32_f16(a, b0, d0, 0, 0, 0);
    d1 = __builtin_amdgcn_mfma_f32_16x16x32_f16(a, b1, d1, 0, 0, 0);
#pragma unroll
    for (int r = 0; r < 4; ++r) {
      const int t = tt * 16 + lk * 4 + r;
      const int dh = dh_of(t), dw = dw_of(t);
      const int h = hi * 16 + dh, w = wi * 16 + dw;
      out[(((size_t)(b * 32 + li)) * 256 + h) * 256 + w] = d0[r];
      out[(((size_t)(b * 32 + 16 + li)) * 256 + h) * 256 + w] = d1[r];
    }
  }
}

// ---------------------------------------------------------------------------
extern "C" void kernel_launch(void* const* d_in, const int* in_sizes, int n_in,
                              void* d_out, int out_size, void* d_ws, size_t ws_size,
                              hipStream_t stream)
{
  const float* x  = (const float*)d_in[0];
  const float* wq = (const float*)d_in[1];
  const float* bq = (const float*)d_in[2];
  const float* wk = (const float*)d_in[3];
  const float* bk = (const float*)d_in[4];
  const float* w1 = (const float*)d_in[5];
  float* out = (float*)d_out;
  char* ws = (char*)d_ws;

  // ws: Qn [0,32M) | Kn [32M,64M) | Vtt [64M,96M) | Spart [96M,104M) | Sh [104M,105M)
  // Y aliases Qn (dead after K2).
  f16*   Qn    = (f16*)(ws);
  f16*   Kn    = (f16*)(ws + 33554432);
  f16*   Vtt   = (f16*)(ws + 67108864);
  float* Spart = (float*)(ws + 100663296);
  f16*   Sh    = (f16*)(ws + 109051904);
  f16*   Y     = Qn;

  k1a_conv<<<4096, 256, 0, stream>>>(x, wq, bq, wk, bk, Qn, Kn, Vtt);
  k2_logits<<<dim3(16, 4, 8), 256, 0, stream>>>(Qn, Kn, Spart);
  k3_softmax<<<512, 256, 0, stream>>>(Spart, Sh);
  k4_ev<<<dim3(64, 2, 8), 256, 0, stream>>>(Vtt, Sh, Y);
  k5_w1_unpermute<<<2048, 256, 0, stream>>>(Y, w1, out);
}

// Round 16
// 136.402 us; speedup vs baseline: 1.9928x; 1.0029x over previous
//
#include <hip/hip_runtime.h>

#define B_ 8
#define C_ 32
#define NI 256   // coarse positions (16x16)
#define C4 8192  // merged channels = 32*256

typedef _Float16 f16;
typedef __attribute__((ext_vector_type(8))) _Float16 f16x8;
typedef __attribute__((ext_vector_type(4))) _Float16 f16x4;
typedef __attribute__((ext_vector_type(2))) _Float16 f16x2;
typedef __attribute__((ext_vector_type(4))) float f32x4;

__device__ __forceinline__ int dh_of(int t) { return (t & 1) | ((t >> 1) & 2) | ((t >> 2) & 4) | ((t >> 3) & 8); }
__device__ __forceinline__ int dw_of(int t) { return ((t >> 1) & 1) | ((t >> 2) & 2) | ((t >> 3) & 4) | ((t >> 4) & 8); }
// xs bank swizzle: permute 16B units within a row (bijective on 0..63)
__device__ __forceinline__ int swzu(int u) { return u ^ ((u >> 3) & 7); }

// async 16B global -> LDS (gfx950). lds must be wave-uniform base; HW adds lane*16.
__device__ __forceinline__ void gld16(const void* g, void* lds) {
  __builtin_amdgcn_global_load_lds(
      (const __attribute__((address_space(1))) unsigned int*)g,
      (__attribute__((address_space(3))) unsigned int*)lds, 16, 0, 0);
}

// ---------------------------------------------------------------------------
// K1a (v5.4): LDS-staged depthwise 3x3 conv + fused Vtt emission.
// Plain __launch_bounds__(256) (rounds 13/14: min-waves>=6 => allocator
// spill pathology; round 15: plain => VGPR=60, no spill, 55us).
// ROUND-16 CHANGE: XOR-swizzle xs 16B units (u ^= (u>>3)&7) -- conv's
// stride-64B row reads were 8-way bank-conflicted (3.54M conflict cycles
// ~ 5.7us/CU serial LDS stall). Pad unit (words 256..259) stays physical
// so the halo trick (unit -1/64 -> zeroed pad) is preserved.
// ---------------------------------------------------------------------------
__global__ __launch_bounds__(256) void k1a_conv(
    const float* __restrict__ x, const float* __restrict__ wq, const float* __restrict__ bq,
    const float* __restrict__ wk, const float* __restrict__ bk,
    f16* __restrict__ Qn, f16* __restrict__ Kn, f16* __restrict__ Vtt)
{
  __shared__ __align__(16) float xs[19 * 260];   // 19.76 KB
  const int bid = blockIdx.x;
  const int hi = bid & 15, c = (bid >> 4) & 31, b = bid >> 9;
  const int tid = threadIdx.x;
  const size_t cimg = ((size_t)(b * 32 + c)) << 16;

  // zero the 4-col pad of every row (left/right-halo source) -- physical pos 256
  if (tid < 19) {
    f32x4 z = {};
    *(f32x4*)&xs[tid * 260 + 256] = z;
  }
  // stage rows 1..18 (strip row rr = gh - (hi*16 - 1)), 1152 f32x4 units
#pragma unroll
  for (int s = 0; s < 5; ++s) {
    const int idx = tid + 256 * s;
    if (idx < 1152) {
      const int rr = idx >> 6;        // 0..17
      const int col4 = idx & 63;
      const int gh = hi * 16 - 1 + rr;
      f32x4 v = {};
      if ((unsigned)gh < 256u)
        v = *(const f32x4*)(x + cimg + (size_t)gh * 256 + col4 * 4);
      *(f32x4*)&xs[(rr + 1) * 260 + (swzu(col4) << 2)] = v;
    }
  }
  __syncthreads();

  // Q/K conv: thread = (hl = tid>>4, wseg = tid&15), 16 outputs along w
  {
    const int hl = tid >> 4, wseg = tid & 15;
    const int w0 = wseg * 16;
    const int ubase = 4 * wseg - 1;
    float q[16], k[16];
    const float bqv = bq[c], bkv = bk[c];
#pragma unroll
    for (int w = 0; w < 16; ++w) { q[w] = bqv; k[w] = bkv; }
#pragma unroll
    for (int dy = 0; dy < 3; ++dy) {
      const float* row = &xs[(hl + 1 + dy) * 260];
      float rbuf[24];   // logical cols w0-4 .. w0+19 (6 swizzled b128 reads)
#pragma unroll
      for (int v6 = 0; v6 < 6; ++v6) {
        const int u = ubase + v6;
        const int off = (u < 0) ? -4 : (u >= 64 ? 256 : (swzu(u) << 2));
        const f32x4 a = *(const f32x4*)(row + off);
#pragma unroll
        for (int e = 0; e < 4; ++e) rbuf[v6 * 4 + e] = a[e];
      }
      const float q0 = wq[c * 9 + dy * 3], q1 = wq[c * 9 + dy * 3 + 1], q2 = wq[c * 9 + dy * 3 + 2];
      const float k0 = wk[c * 9 + dy * 3], k1 = wk[c * 9 + dy * 3 + 1], k2 = wk[c * 9 + dy * 3 + 2];
#pragma unroll
      for (int w = 0; w < 16; ++w) {   // col w0+w-1 = rbuf[3+w]
        q[w] += rbuf[3 + w] * q0 + rbuf[4 + w] * q1 + rbuf[5 + w] * q2;
        k[w] += rbuf[3 + w] * k0 + rbuf[4 + w] * k1 + rbuf[5 + w] * k2;
      }
    }
    f16x8 qo[2], ko[2];
#pragma unroll
    for (int w = 0; w < 16; ++w) { qo[w >> 3][w & 7] = (f16)q[w]; ko[w >> 3][w & 7] = (f16)k[w]; }
    f16* qp = Qn + cimg + (size_t)(hi * 16 + hl) * 256 + w0;
    f16* kp = Kn + cimg + (size_t)(hi * 16 + hl) * 256 + w0;
    *(f16x8*)qp = qo[0]; *(f16x8*)(qp + 8) = qo[1];
    *(f16x8*)kp = ko[0]; *(f16x8*)(kp + 8) = ko[1];
  }

  {  // Vtt[b][t*32+c][hi*16+wi] = xs[dh(t)+2][wi*16+dw(t)] (swizzled word addr)
    const int t = tid;
    const int dh = dh_of(t), dw = dw_of(t);
    const float* rowp = &xs[(dh + 2) * 260];
    f16x8 o0, o1;
#pragma unroll
    for (int wi = 0; wi < 16; ++wi) {
      const int wcol = wi * 16 + dw;
      const f16 v = (f16)rowp[(swzu(wcol >> 2) << 2) | (wcol & 3)];
      if (wi < 8) o0[wi] = v; else o1[wi - 8] = v;
    }
    f16* vdst = Vtt + ((size_t)b * C4 + (size_t)t * 32 + c) * 256 + hi * 16;
    *(f16x8*)vdst = o0;
    *(f16x8*)(vdst + 8) = o1;
  }
}

// ---------------------------------------------------------------------------
// K2: logits partials from NATURAL-layout Qn/Kn. Split-K by 4.
// ---------------------------------------------------------------------------
__global__ __launch_bounds__(256) void k2_logits(
    const f16* __restrict__ Qn, const f16* __restrict__ Kn, float* __restrict__ Spart)
{
  const int b = blockIdx.z;
  const int kt = blockIdx.y;
  const int it = blockIdx.x >> 2, jt = blockIdx.x & 3;
  const int tid = threadIdx.x, wave = tid >> 6, lane = tid & 63;
  const int li = lane & 15, lk = lane >> 4;
  const int i0 = it * 64 + wave * 16;
  const int j0 = jt * 64;
  const f16* Qb = Qn + ((size_t)b << 21);
  const f16* Kb = Kn + ((size_t)b << 21);
  const int dhl = lk >> 1, dwl = (lk & 1) * 8;

  f32x4 acc[4] = {};
  const int kbeg = kt * 2048, kend = kbeg + 2048;
  for (int kk = kbeg; kk < kend; kk += 32) {
    const int c = kk >> 8, dhb = (kk >> 4) & 15;
    const size_t cbase = ((size_t)c << 16) + (size_t)(dhb + dhl) * 256 + li * 16 + dwl;
    const f16x8 a = *(const f16x8*)(Qb + cbase + (size_t)i0 * 256);
#pragma unroll
    for (int jj = 0; jj < 4; ++jj) {
      const f16x8 bb = *(const f16x8*)(Kb + cbase + (size_t)(j0 + jj * 16) * 256);
      acc[jj] = __builtin_amdgcn_mfma_f32_16x16x32_f16(a, bb, acc[jj], 0, 0, 0);
    }
  }
  float* Sp = Spart + ((size_t)kt * B_ + b) * NI * NI;
#pragma unroll
  for (int jj = 0; jj < 4; ++jj)
#pragma unroll
    for (int r = 0; r < 4; ++r) {
      const int ii = i0 + lk * 4 + r;
      const int jc = j0 + jj * 16 + li;
      Sp[(size_t)ii * NI + jc] = acc[jj][r];
    }
}

// ---------------------------------------------------------------------------
// K3: sum 4 partials + softmax over j (256), write f16. One wave per row.
// ---------------------------------------------------------------------------
__global__ __launch_bounds__(256) void k3_softmax(
    const float* __restrict__ Spart, f16* __restrict__ Sh)
{
  const int row = blockIdx.x * 4 + (threadIdx.x >> 6);  // 2048 rows
  const int lane = threadIdx.x & 63;
  const size_t base = (size_t)row * NI + lane * 4;
  f32x4 v = {0.f, 0.f, 0.f, 0.f};
#pragma unroll
  for (int kt = 0; kt < 4; ++kt) {
    const f32x4 p = *(const f32x4*)(Spart + (size_t)kt * B_ * NI * NI + base);
    v[0] += p[0]; v[1] += p[1]; v[2] += p[2]; v[3] += p[3];
  }
  float m = fmaxf(fmaxf(v[0], v[1]), fmaxf(v[2], v[3]));
#pragma unroll
  for (int d = 1; d < 64; d <<= 1) m = fmaxf(m, __shfl_xor(m, d, 64));
  const float e0 = expf(v[0] - m), e1 = expf(v[1] - m), e2 = expf(v[2] - m), e3 = expf(v[3] - m);
  float s = e0 + e1 + e2 + e3;
#pragma unroll
  for (int d = 1; d < 64; d <<= 1) s += __shfl_xor(s, d, 64);
  const float inv = 1.f / s;
  f16x4 o;
  o[0] = (f16)(e0 * inv); o[1] = (f16)(e1 * inv); o[2] = (f16)(e2 * inv); o[3] = (f16)(e3 * inv);
  *(f16x4*)(Sh + (size_t)row * NI + lane * 4) = o;
}

// ---------------------------------------------------------------------------
// K4 (m97-structure + fused residual): per-batch GEMM
// Y[i][c4] = sum_j Vtt[c4][j]*Sh[i][j] + Vtt[c4][i].
// Block tile 128x128, BK=64, global_load_lds staging, 2-barrier K-loop.
// ---------------------------------------------------------------------------
__global__ __launch_bounds__(256) void k4_ev(
    const f16* __restrict__ Vtt, const f16* __restrict__ Sh, f16* __restrict__ Y)
{
  __shared__ __align__(16) f16 As[128 * 64];  // [m][k] linear, 16 KB
  __shared__ __align__(16) f16 Bs[128 * 64];  // [n][k] linear, 16 KB
  const int mt = blockIdx.x, nt = blockIdx.y, b = blockIdx.z;
  const int m0 = mt * 128, n0 = nt * 128;
  const int tid = threadIdx.x, wave = tid >> 6, lane = tid & 63;
  const int li = lane & 15, lk = lane >> 4;
  const int wm = wave >> 1, wn = wave & 1;
  const f16* Va  = Vtt + (size_t)b * C4 * NI;
  const f16* Shb = Sh + (size_t)b * NI * NI;

  const int srow = tid >> 3, scol = (tid & 7) * 8;

  f32x4 acc[4][4] = {};

#define K4_STAGE(k0)                                                          \
  {                                                                           \
    _Pragma("unroll")                                                         \
    for (int j = 0; j < 4; ++j) {                                             \
      const int rg = j * 32 + srow;                                           \
      gld16(Va + (size_t)(m0 + rg) * NI + (k0) + scol,                        \
            (char*)As + j * 4096 + wave * 1024);                              \
      gld16(Shb + (size_t)(n0 + rg) * NI + (k0) + scol,                       \
            (char*)Bs + j * 4096 + wave * 1024);                              \
    }                                                                         \
  }

  K4_STAGE(0);
#pragma unroll
  for (int kt = 0; kt < 4; ++kt) {
    __syncthreads();
#pragma unroll
    for (int kh = 0; kh < 2; ++kh) {
      f16x8 af[4], bf[4];
#pragma unroll
      for (int mi = 0; mi < 4; ++mi)
        af[mi] = *(const f16x8*)&As[(wm * 64 + mi * 16 + li) * 64 + kh * 32 + lk * 8];
#pragma unroll
      for (int ni = 0; ni < 4; ++ni)
        bf[ni] = *(const f16x8*)&Bs[(wn * 64 + ni * 16 + li) * 64 + kh * 32 + lk * 8];
#pragma unroll
      for (int mi = 0; mi < 4; ++mi)
#pragma unroll
        for (int ni = 0; ni < 4; ++ni)
          acc[mi][ni] = __builtin_amdgcn_mfma_f32_16x16x32_f16(af[mi], bf[ni], acc[mi][ni], 0, 0, 0);
    }
    __syncthreads();
    if (kt < 3) K4_STAGE((kt + 1) * 64);
  }
#undef K4_STAGE

#pragma unroll
  for (int mi = 0; mi < 4; ++mi)
#pragma unroll
    for (int ni = 0; ni < 4; ++ni) {
      const int i = n0 + wn * 64 + ni * 16 + li;
      const int m = m0 + wm * 64 + mi * 16 + lk * 4;
      const f16* vres = Va + (size_t)m * NI + i;   // Vtt[b][m+r][i]
      f16x4 p;
#pragma unroll
      for (int r = 0; r < 4; ++r)
        p[r] = (f16)(acc[mi][ni][r] + (float)vres[(size_t)r * NI]);
      *(f16x4*)(Y + ((size_t)(b * NI + i)) * C4 + m) = p;
    }
}

// ---------------------------------------------------------------------------
// K5: out[b,o,h,w] = sum_ci w1[o,ci] * Y[b, i(h,w), t(h,w)*32+ci], fp32.
// (Residual folded into Y by K4.) block = (b, i): full 64B-line coverage.
// ---------------------------------------------------------------------------
__global__ __launch_bounds__(256) void k5_w1_unpermute(
    const f16* __restrict__ Y, const float* __restrict__ w1, float* __restrict__ out)
{
  __shared__ f16 w1s[32 * 32];
  const int bid = blockIdx.x;
  const int b = bid >> 8, i = bid & 255;
  const int hi = i >> 4, wi = i & 15;
  const int tid = threadIdx.x;
#pragma unroll
  for (int e = 0; e < 4; ++e) w1s[tid + 256 * e] = (f16)w1[tid + 256 * e];
  __syncthreads();

  const int wave = tid >> 6, lane = tid & 63, li = lane & 15, lk = lane >> 4;
  const f16* Yrow = Y + ((size_t)(b * NI + i)) * C4;
  const f16x8 b0 = *(const f16x8*)(&w1s[li * 32 + lk * 8]);         // o = li
  const f16x8 b1 = *(const f16x8*)(&w1s[(16 + li) * 32 + lk * 8]);  // o = 16+li

#pragma unroll
  for (int q = 0; q < 4; ++q) {
    const int tt = wave * 4 + q;
    const f16x8 a = *(const f16x8*)(Yrow + (size_t)(tt * 16 + li) * 32 + lk * 8);
    f32x4 d0 = {}, d1 = {};
    d0 = __builtin_amdgcn_mfma_f32_16x16x32_f16(a, b0, d0, 0, 0, 0);
    d1 = __builtin_amdgcn_mfma_f32_16x16x32_f16(a, b1, d1, 0, 0, 0);
#pragma unroll
    for (int r = 0; r < 4; ++r) {
      const int t = tt * 16 + lk * 4 + r;
      const int dh = dh_of(t), dw = dw_of(t);
      const int h = hi * 16 + dh, w = wi * 16 + dw;
      out[(((size_t)(b * 32 + li)) * 256 + h) * 256 + w] = d0[r];
      out[(((size_t)(b * 32 + 16 + li)) * 256 + h) * 256 + w] = d1[r];
    }
  }
}

// ---------------------------------------------------------------------------
extern "C" void kernel_launch(void* const* d_in, const int* in_sizes, int n_in,
                              void* d_out, int out_size, void* d_ws, size_t ws_size,
                              hipStream_t stream)
{
  const float* x  = (const float*)d_in[0];
  const float* wq = (const float*)d_in[1];
  const float* bq = (const float*)d_in[2];
  const float* wk = (const float*)d_in[3];
  const float* bk = (const float*)d_in[4];
  const float* w1 = (const float*)d_in[5];
  float* out = (float*)d_out;
  char* ws = (char*)d_ws;

  // ws: Qn [0,32M) | Kn [32M,64M) | Vtt [64M,96M) | Spart [96M,104M) | Sh [104M,105M)
  // Y aliases Qn (dead after K2).
  f16*   Qn    = (f16*)(ws);
  f16*   Kn    = (f16*)(ws + 33554432);
  f16*   Vtt   = (f16*)(ws + 67108864);
  float* Spart = (float*)(ws + 100663296);
  f16*   Sh    = (f16*)(ws + 109051904);
  f16*   Y     = Qn;

  k1a_conv<<<4096, 256, 0, stream>>>(x, wq, bq, wk, bk, Qn, Kn, Vtt);
  k2_logits<<<dim3(16, 4, 8), 256, 0, stream>>>(Qn, Kn, Spart);
  k3_softmax<<<512, 256, 0, stream>>>(Spart, Sh);
  k4_ev<<<dim3(64, 2, 8), 256, 0, stream>>>(Vtt, Sh, Y);
  k5_w1_unpermute<<<2048, 256, 0, stream>>>(Y, w1, out);
}